// Round 11
// baseline (1451564.648 us; speedup 1.0000x reference)
//
#include <hip/hip_runtime.h>

// LSTM H=512, B=256, T=256, D_IN=10, C=10. fp32 in/out.
// R11 = R10 resubmission (R10 hit the known-dead container 'crisp-trim-mellow-
// exam' - "first message" connect failure; kernel never ran).
// XCD-local recurrence: each physical XCD (HW_REG_XCC_ID) owns one 32-column
// group; its 32 WGs (rank via per-XCD atomic; 1 WG/CU capacity => exactly
// 32/XCD) cover all 2048 stacked rows. h exchanged through the XCD's own L2
// via sc0 ops (L1-bypass, L2-coherent): batched global_load_dwordx4 sc0 (one
// vmcnt per step), global_store_short sc0, sc0 flag store/poll. No L3/agent
// traffic in the hot loop. Numerics identical to R9 (h-hi bf16 exchange,
// W hi+lo in LDS, x hi+lo). All loops bounded - cannot wedge the GPU.

#define Hdim 512
#define Bdim 256
#define Tdim 256
#define Kpad 544          // 512 (h) + 32 (x: 10 real + 22 zero)
#define LROW 552          // LDS row stride (shorts)
#define LDS_BYTES (64 * LROW * 2 * 2)   // hi+lo, 64 rows: 141,312 B -> 1 WG/CU

typedef __bf16 bf16x8 __attribute__((ext_vector_type(8)));
typedef float f32x4 __attribute__((ext_vector_type(4)));
typedef unsigned long long u64;

__device__ __forceinline__ unsigned short f2bf(float f) {
    union { float f; unsigned u; } x; x.f = f;
    unsigned r = x.u + 0x7FFFu + ((x.u >> 16) & 1u);
    return (unsigned short)(r >> 16);
}
__device__ __forceinline__ float bf2f(unsigned short h) {
    union { unsigned u; float f; } x; x.u = ((unsigned)h) << 16;
    return x.f;
}
__device__ __forceinline__ bf16x8 ld8(const unsigned short* p) {
    return *reinterpret_cast<const bf16x8*>(p);
}
__device__ __forceinline__ bf16x8 asbf(f32x4 v) {
    union { f32x4 f; bf16x8 b; } u; u.f = v; return u.b;
}
__device__ __forceinline__ f32x4 mfma16(bf16x8 a, bf16x8 b, f32x4 c) {
    return __builtin_amdgcn_mfma_f32_16x16x32_bf16(a, b, c, 0, 0, 0);
}
__device__ __forceinline__ float sigm(float x) { return 1.f / (1.f + __expf(-x)); }
__device__ __forceinline__ float tanh_fast(float x) {
    return 2.f / (1.f + __expf(-2.f * x)) - 1.f;
}
// sc0 store of one bf16 (write-through to this XCD's L2)
__device__ __forceinline__ void stL2(unsigned short* p, unsigned short v) {
    unsigned vv = v;
    asm volatile("global_store_short %0, %1, off sc0" :: "v"(p), "v"(vv) : "memory");
}

// ---------- prep: stacked gate weights -> bf16 hi/lo, row = 4*i + gate ----------
__global__ void k_prep_w(const float* __restrict__ w_gh, const float* __restrict__ w_ih,
                         const float* __restrict__ w_fh, const float* __restrict__ w_oh,
                         const float* __restrict__ w_gx, const float* __restrict__ w_ix,
                         const float* __restrict__ w_fx, const float* __restrict__ w_ox,
                         unsigned short* __restrict__ Whi, unsigned short* __restrict__ Wlo) {
    int idx = blockIdx.x * 256 + threadIdx.x;
    if (idx >= 2048 * Kpad) return;
    int rw = idx / Kpad;
    int k  = idx % Kpad;
    int gate = rw & 3;
    int i = rw >> 2;
    float v = 0.f;
    if (k < 512) {
        const float* wh = (gate == 0) ? w_gh : (gate == 1) ? w_ih : (gate == 2) ? w_fh : w_oh;
        v = wh[i * 512 + k];
    } else if (k < 522) {
        const float* wx = (gate == 0) ? w_gx : (gate == 1) ? w_ix : (gate == 2) ? w_fx : w_ox;
        v = wx[i * 10 + (k - 512)];
    }
    unsigned short hi = f2bf(v);
    unsigned short lo = f2bf(v - bf2f(hi));
    Whi[idx] = hi;
    Wlo[idx] = lo;
}

// ---------- prep: x -> Xhi/Xlo [t][b][32] ----------
__global__ void k_prep_x(const float* __restrict__ x,
                         unsigned short* __restrict__ Xhi, unsigned short* __restrict__ Xlo) {
    int idx = blockIdx.x * 256 + threadIdx.x;
    if (idx >= Tdim * Bdim * 32) return;
    int j = idx & 31;
    int b = (idx >> 5) & 255;
    int t = idx >> 13;
    float v = 0.f;
    if (j < 10) v = x[(b * Tdim + t) * 10 + j];
    unsigned short hi = f2bf(v);
    unsigned short lo = f2bf(v - bf2f(hi));
    Xhi[idx] = hi;
    Xlo[idx] = lo;
}

__global__ void k_zero(float* __restrict__ p) {
    p[blockIdx.x * 256 + threadIdx.x] = 0.f;
}

// ---------- persistent LSTM ----------
// 256 WGs x 256 thr. WG: 64 stacked rows x 32 cols. Waves 2x2: 32 rows x 16 cols.
__global__ __launch_bounds__(256, 1) void k_persist(
    const unsigned short* __restrict__ Whi, const unsigned short* __restrict__ Wlo,
    const unsigned short* __restrict__ Xhi, const unsigned short* __restrict__ Xlo,
    unsigned short* H0hi, unsigned short* H1hi,
    float* __restrict__ Hf32,
    const float* __restrict__ bg, const float* __restrict__ bi,
    const float* __restrict__ bf_, const float* __restrict__ bo,
    unsigned* flags, unsigned* xcnt) {
    extern __shared__ unsigned short lds[];
    unsigned short* Lhi = lds;                 // [64][LROW]
    unsigned short* Llo = lds + 64 * LROW;
    __shared__ unsigned srank_s;

    const int tid = threadIdx.x;
    const int lane = tid & 63;
    const int wv = tid >> 6;
    const int wm = wv >> 1, wn = wv & 1;
    const int lr = lane & 15, q = lane >> 4;

    // physical XCD id + rank among the 32 WGs resident on this XCD
    unsigned xcd;
    asm volatile("s_getreg_b32 %0, hwreg(HW_REG_XCC_ID)" : "=s"(xcd));
    xcd &= 7u;
    if (tid == 0) srank_s = atomicAdd(&xcnt[xcd], 1u);
    __syncthreads();
    const int rank = (int)(srank_s & 31u);     // row-group id (0..31)
    const int m0  = rank * 64;                 // stacked-row tile base
    const int bn0 = (int)xcd * 32;             // column tile base = XCD slice

    // flags: one 64B line per WG: index (xcd*32+rank)*16 uints
    unsigned* myflag = flags + ((((int)xcd << 5) + rank) << 4);
    unsigned* pollp  = flags + ((((int)xcd << 5) + (lane & 31)) << 4);

    // one-time weight staging global -> LDS
    for (int it = tid; it < 64 * 68; it += 256) {
        int r = it / 68, c8 = (it % 68) * 8;
        *(bf16x8*)&Lhi[r * LROW + c8] = ld8(Whi + (size_t)(m0 + r) * Kpad + c8);
        *(bf16x8*)&Llo[r * LROW + c8] = ld8(Wlo + (size_t)(m0 + r) * Kpad + c8);
    }
    __syncthreads();

    const int colc = bn0 + wn * 16 + lr;       // this lane's column
    const int row0 = wm * 32;                  // local A-row base for this wave
    const int i0 = (m0 >> 2) + wm * 8 + q;     // h-row of frag0 cell
    const int i1 = i0 + 4;                     // h-row of frag1 cell
    const int kq = q * 8;

    float c0 = 0.f, c1 = 0.f;
    const f32x4 binit0 = { bg[i0], bi[i0], bf_[i0], bo[i0] };
    const f32x4 binit1 = { bg[i1], bi[i1], bf_[i1], bo[i1] };

    const unsigned short* A0h = &Lhi[(row0 + lr) * LROW + kq];
    const unsigned short* A0l = &Llo[(row0 + lr) * LROW + kq];
    const unsigned short* A1h = A0h + 16 * LROW;
    const unsigned short* A1l = A0l + 16 * LROW;

    for (int t = 0; t < Tdim; ++t) {
        const unsigned short* Rh = (t & 1) ? H1hi : H0hi;
        unsigned short* Wh = (t & 1) ? H0hi : H1hi;
        const unsigned short* Bp = Rh + (size_t)colc * Hdim + kq;
        const unsigned short* XbH = Xhi + ((size_t)t * Bdim + colc) * 32 + kq;
        const unsigned short* XbL = Xlo + ((size_t)t * Bdim + colc) * 32 + kq;

        // ---- phase 1: 16 x 16B sc0 loads (L2), one vmcnt for all ----
        f32x4 b0,b1,b2,b3,b4,b5,b6,b7,b8,b9,b10,b11,b12,b13,b14,b15;
        asm volatile(
            "global_load_dwordx4 %0,  %16, off sc0\n\t"
            "global_load_dwordx4 %1,  %16, off offset:64 sc0\n\t"
            "global_load_dwordx4 %2,  %16, off offset:128 sc0\n\t"
            "global_load_dwordx4 %3,  %16, off offset:192 sc0\n\t"
            "global_load_dwordx4 %4,  %16, off offset:256 sc0\n\t"
            "global_load_dwordx4 %5,  %16, off offset:320 sc0\n\t"
            "global_load_dwordx4 %6,  %16, off offset:384 sc0\n\t"
            "global_load_dwordx4 %7,  %16, off offset:448 sc0\n\t"
            "global_load_dwordx4 %8,  %16, off offset:512 sc0\n\t"
            "global_load_dwordx4 %9,  %16, off offset:576 sc0\n\t"
            "global_load_dwordx4 %10, %16, off offset:640 sc0\n\t"
            "global_load_dwordx4 %11, %16, off offset:704 sc0\n\t"
            "global_load_dwordx4 %12, %16, off offset:768 sc0\n\t"
            "global_load_dwordx4 %13, %16, off offset:832 sc0\n\t"
            "global_load_dwordx4 %14, %16, off offset:896 sc0\n\t"
            "global_load_dwordx4 %15, %16, off offset:960 sc0\n\t"
            "s_waitcnt vmcnt(0)"
            : "=v"(b0),"=v"(b1),"=v"(b2),"=v"(b3),"=v"(b4),"=v"(b5),"=v"(b6),"=v"(b7),
              "=v"(b8),"=v"(b9),"=v"(b10),"=v"(b11),"=v"(b12),"=v"(b13),"=v"(b14),"=v"(b15)
            : "v"(Bp));
        bf16x8 xh = ld8(XbH), xl = ld8(XbL);   // x: read-only, ordinary cached load

        // ---- phase 2: MFMA (W hi+lo from LDS, B = h-hi from L2) ----
        f32x4 acc0 = binit0, acc1 = binit1;
#define KSTEP(KB, BREG) { \
        const int k = (KB) * 32; \
        bf16x8 a0h = ld8(A0h + k), a0l = ld8(A0l + k); \
        bf16x8 a1h = ld8(A1h + k), a1l = ld8(A1l + k); \
        bf16x8 bh = asbf(BREG); \
        acc0 = mfma16(a0h, bh, acc0); \
        acc1 = mfma16(a1h, bh, acc1); \
        acc0 = mfma16(a0l, bh, acc0); \
        acc1 = mfma16(a1l, bh, acc1); }
        KSTEP(0,b0)  KSTEP(1,b1)  KSTEP(2,b2)  KSTEP(3,b3)
        KSTEP(4,b4)  KSTEP(5,b5)  KSTEP(6,b6)  KSTEP(7,b7)
        KSTEP(8,b8)  KSTEP(9,b9)  KSTEP(10,b10) KSTEP(11,b11)
        KSTEP(12,b12) KSTEP(13,b13) KSTEP(14,b14) KSTEP(15,b15)
#undef KSTEP
        {   // x tail (k block 16): x keeps hi+lo
            const int k = 512;
            bf16x8 a0h = ld8(A0h + k), a0l = ld8(A0l + k);
            bf16x8 a1h = ld8(A1h + k), a1l = ld8(A1l + k);
            acc0 = mfma16(a0h, xh, acc0);
            acc1 = mfma16(a1h, xh, acc1);
            acc0 = mfma16(a0h, xl, acc0);
            acc1 = mfma16(a1h, xl, acc1);
            acc0 = mfma16(a0l, xh, acc0);
            acc1 = mfma16(a1l, xh, acc1);
        }

        {   // frag0 cell update (h-row i0, col colc)
            float g = tanh_fast(acc0[0]), ii = sigm(acc0[1]);
            float f = sigm(acc0[2]),      o  = sigm(acc0[3]);
            c0 = g * ii + c0 * f;
            float h = tanh_fast(c0) * o;
            size_t idx = (size_t)colc * Hdim + i0;
            stL2(Wh + idx, f2bf(h));
            if (t == Tdim - 1) Hf32[idx] = h;
        }
        {   // frag1 cell update (h-row i1, col colc)
            float g = tanh_fast(acc1[0]), ii = sigm(acc1[1]);
            float f = sigm(acc1[2]),      o  = sigm(acc1[3]);
            c1 = g * ii + c1 * f;
            float h = tanh_fast(c1) * o;
            size_t idx = (size_t)colc * Hdim + i1;
            stL2(Wh + idx, f2bf(h));
            if (t == Tdim - 1) Hf32[idx] = h;
        }

        // ---- XCD-local barrier: per-WG flags in L2 + wave0 parallel poll ----
        asm volatile("s_waitcnt vmcnt(0)" ::: "memory");  // h stores landed in L2
        __syncthreads();                                  // all waves drained
        if (wv == 0) {
            if (lane == 0) {
                unsigned gen = (unsigned)(t + 1);
                asm volatile("global_store_dword %0, %1, off sc0"
                             :: "v"(myflag), "v"(gen) : "memory");
            }
            const unsigned tgt = (unsigned)(t + 1);
            bool ok = lane >= 32;                         // lanes 0..31 poll WG lane
            int guard = 1 << 16;  // bounded: pathological case -> no hang
            while (!ok && --guard) {
                unsigned v;
                asm volatile("global_load_dword %0, %1, off sc0\n\t"
                             "s_waitcnt vmcnt(0)" : "=v"(v) : "v"(pollp));
                ok = (v >= tgt);
                if (!ok) __builtin_amdgcn_s_sleep(1);     // pace the L2 traffic
            }
        }
        __syncthreads();
        asm volatile("" ::: "memory");   // no B-load hoisting above the barrier
    }
}

// ---------- output: logits + softmax, one block per batch element ----------
__global__ __launch_bounds__(64) void k_out(
    const float* __restrict__ Hf32, const float* __restrict__ w_out,
    const float* __restrict__ b_out, float* __restrict__ out) {
    int b = blockIdx.x;
    int lane = threadIdx.x;
    const f32x4* h4 = (const f32x4*)(Hf32 + (size_t)b * 512);
    f32x4 h0 = h4[lane * 2], h1 = h4[lane * 2 + 1];
    float acc[10];
#pragma unroll
    for (int c = 0; c < 10; ++c) {
        const f32x4* w4 = (const f32x4*)(w_out + c * 512);
        f32x4 w0 = w4[lane * 2], w1 = w4[lane * 2 + 1];
        acc[c] = h0[0]*w0[0] + h0[1]*w0[1] + h0[2]*w0[2] + h0[3]*w0[3]
               + h1[0]*w1[0] + h1[1]*w1[1] + h1[2]*w1[2] + h1[3]*w1[3];
    }
#pragma unroll
    for (int s = 32; s >= 1; s >>= 1)
#pragma unroll
        for (int c = 0; c < 10; ++c) acc[c] += __shfl_xor(acc[c], s, 64);
    if (lane == 0) {
        float logit[10];
#pragma unroll
        for (int c = 0; c < 10; ++c) logit[c] = acc[c] + b_out[c];
        float m = logit[0];
#pragma unroll
        for (int c = 1; c < 10; ++c) m = fmaxf(m, logit[c]);
        float e[10], sum = 0.f;
#pragma unroll
        for (int c = 0; c < 10; ++c) { e[c] = __expf(logit[c] - m); sum += e[c]; }
        float inv = 1.f / sum;
#pragma unroll
        for (int c = 0; c < 10; ++c) out[b * 10 + c] = e[c] * inv;
    }
}

extern "C" void kernel_launch(void* const* d_in, const int* in_sizes, int n_in,
                              void* d_out, int out_size, void* d_ws, size_t ws_size,
                              hipStream_t stream) {
    const float* x    = (const float*)d_in[0];
    const float* w_gx = (const float*)d_in[1];
    const float* w_gh = (const float*)d_in[2];
    const float* b_g  = (const float*)d_in[3];
    const float* w_ix = (const float*)d_in[4];
    const float* w_ih = (const float*)d_in[5];
    const float* b_i  = (const float*)d_in[6];
    const float* w_fx = (const float*)d_in[7];
    const float* w_fh = (const float*)d_in[8];
    const float* b_f  = (const float*)d_in[9];
    const float* w_ox = (const float*)d_in[10];
    const float* w_oh = (const float*)d_in[11];
    const float* b_o  = (const float*)d_in[12];
    const float* w_out = (const float*)d_in[13];
    const float* b_out = (const float*)d_in[14];
    float* out = (float*)d_out;

    char* ws = (char*)d_ws;
    size_t off = 0;
    auto alloc = [&](size_t bytes) { void* p = ws + off; off += (bytes + 255) & ~255ull; return p; };
    // flags | xcnt | H0hi contiguous -> one zeroing kernel covers all three
    unsigned*       flags = (unsigned*)alloc(16384);      // 256 WG-flags, 64B apart
    unsigned*       xcnt  = (unsigned*)alloc(256);        // 8 per-XCD rank counters
    unsigned short* H0hi  = (unsigned short*)alloc((size_t)Bdim * 512 * 2);
    unsigned short* H1hi  = (unsigned short*)alloc((size_t)Bdim * 512 * 2);
    float*          Hf32  = (float*)alloc((size_t)Bdim * 512 * 4);
    unsigned short* Whi   = (unsigned short*)alloc(2048ull * Kpad * 2);
    unsigned short* Wlo   = (unsigned short*)alloc(2048ull * Kpad * 2);
    unsigned short* Xhi   = (unsigned short*)alloc((size_t)Tdim * Bdim * 32 * 2);
    unsigned short* Xlo   = (unsigned short*)alloc((size_t)Tdim * Bdim * 32 * 2);
    (void)ws_size; (void)in_sizes; (void)n_in; (void)out_size;

    k_prep_w<<<(2048 * Kpad + 255) / 256, 256, 0, stream>>>(
        w_gh, w_ih, w_fh, w_oh, w_gx, w_ix, w_fx, w_ox, Whi, Wlo);
    k_prep_x<<<(Tdim * Bdim * 32 + 255) / 256, 256, 0, stream>>>(x, Xhi, Xlo);
    // zero flags+xcnt+H0hi: 16384+256+262144 B = 278,784 B; 273 blocks covers
    // 279,552 B (spills 768 B into H1hi - harmless, H1hi fully written at t=0)
    k_zero<<<273, 256, 0, stream>>>((float*)flags);

    hipFuncSetAttribute((const void*)k_persist,
                        hipFuncAttributeMaxDynamicSharedMemorySize, LDS_BYTES);
    k_persist<<<dim3(256), dim3(256), LDS_BYTES, stream>>>(
        Whi, Wlo, Xhi, Xlo, H0hi, H1hi,
        Hf32, b_g, b_i, b_f, b_o, flags, xcnt);

    k_out<<<256, 64, 0, stream>>>(Hf32, w_out, b_out, out);
}

// Round 12
// 1609.960 us; speedup vs baseline: 901.6151x; 901.6151x over previous
//
#include <hip/hip_runtime.h>

// LSTM H=512, B=256, T=256, D_IN=10, C=10. fp32 in/out.
// R12: R9 fabric (agent-scope atomics to L3, per-WG flag barrier - PROVEN;
// R11 taught: sc0 polling reads stale L1 forever) + LDS-staged B panel to
// remove the 2x intra-WG duplication: 16MB/step -> 8MB/step, coalesced.
// WG = 64 stacked rows x 32 cols; wave w owns rows w*16..w*16+15 (R1-verified
// fragment map); each lane outputs cells (i, col0) and (i, col0+16).
// Panel: one 16.7KB LDS buffer, halves staged sequentially (cols 0-15, 16-31),
// sourced by batched agent u64 loads (16/thread, all in flight at step start).

#define Hdim 512
#define Bdim 256
#define Tdim 256
#define Kpad 544          // 512 (h) + 32 (x: 10 real + 22 zero)
#define LROW 552          // weight LDS row stride (shorts): 2-way banks only
#define PROW 536          // panel LDS col stride (shorts): 16B-mult, 2-way banks
#define LDS_BYTES ((64 * LROW * 2 + 16 * PROW) * 2)   // 158,464 B -> 1 WG/CU

typedef __bf16 bf16x8 __attribute__((ext_vector_type(8)));
typedef float f32x4 __attribute__((ext_vector_type(4)));
typedef unsigned long long u64;

__device__ __forceinline__ unsigned short f2bf(float f) {
    union { float f; unsigned u; } x; x.f = f;
    unsigned r = x.u + 0x7FFFu + ((x.u >> 16) & 1u);
    return (unsigned short)(r >> 16);
}
__device__ __forceinline__ float bf2f(unsigned short h) {
    union { unsigned u; float f; } x; x.u = ((unsigned)h) << 16;
    return x.f;
}
__device__ __forceinline__ bf16x8 ld8(const unsigned short* p) {
    return *reinterpret_cast<const bf16x8*>(p);
}
__device__ __forceinline__ u64 ldA(const u64* p) {   // L2-bypass 8B load (L3)
    return __hip_atomic_load(p, __ATOMIC_RELAXED, __HIP_MEMORY_SCOPE_AGENT);
}
// write-through 2B store (agent scope -> lands at L3)
__device__ __forceinline__ void stH(unsigned short* p, unsigned short v) {
    __hip_atomic_store(p, v, __ATOMIC_RELAXED, __HIP_MEMORY_SCOPE_AGENT);
}
__device__ __forceinline__ f32x4 mfma16(bf16x8 a, bf16x8 b, f32x4 c) {
    return __builtin_amdgcn_mfma_f32_16x16x32_bf16(a, b, c, 0, 0, 0);
}
__device__ __forceinline__ float sigm(float x) { return 1.f / (1.f + __expf(-x)); }
__device__ __forceinline__ float tanh_fast(float x) {
    return 2.f / (1.f + __expf(-2.f * x)) - 1.f;
}

// ---------- prep: stacked gate weights -> bf16 hi/lo, row = 4*i + gate ----------
__global__ void k_prep_w(const float* __restrict__ w_gh, const float* __restrict__ w_ih,
                         const float* __restrict__ w_fh, const float* __restrict__ w_oh,
                         const float* __restrict__ w_gx, const float* __restrict__ w_ix,
                         const float* __restrict__ w_fx, const float* __restrict__ w_ox,
                         unsigned short* __restrict__ Whi, unsigned short* __restrict__ Wlo) {
    int idx = blockIdx.x * 256 + threadIdx.x;
    if (idx >= 2048 * Kpad) return;
    int rw = idx / Kpad;
    int k  = idx % Kpad;
    int gate = rw & 3;
    int i = rw >> 2;
    float v = 0.f;
    if (k < 512) {
        const float* wh = (gate == 0) ? w_gh : (gate == 1) ? w_ih : (gate == 2) ? w_fh : w_oh;
        v = wh[i * 512 + k];
    } else if (k < 522) {
        const float* wx = (gate == 0) ? w_gx : (gate == 1) ? w_ix : (gate == 2) ? w_fx : w_ox;
        v = wx[i * 10 + (k - 512)];
    }
    unsigned short hi = f2bf(v);
    unsigned short lo = f2bf(v - bf2f(hi));
    Whi[idx] = hi;
    Wlo[idx] = lo;
}

// ---------- prep: x -> Xhi/Xlo [t][b][32] ----------
__global__ void k_prep_x(const float* __restrict__ x,
                         unsigned short* __restrict__ Xhi, unsigned short* __restrict__ Xlo) {
    int idx = blockIdx.x * 256 + threadIdx.x;
    if (idx >= Tdim * Bdim * 32) return;
    int j = idx & 31;
    int b = (idx >> 5) & 255;
    int t = idx >> 13;
    float v = 0.f;
    if (j < 10) v = x[(b * Tdim + t) * 10 + j];
    unsigned short hi = f2bf(v);
    unsigned short lo = f2bf(v - bf2f(hi));
    Xhi[idx] = hi;
    Xlo[idx] = lo;
}

__global__ void k_zero(float* __restrict__ p) {
    p[blockIdx.x * 256 + threadIdx.x] = 0.f;
}

// ---------- persistent LSTM ----------
// 256 WGs x 256 thr. WG: 64 stacked rows x 32 cols. Wave w: rows w*16..+15.
__global__ __launch_bounds__(256, 1) void k_persist(
    const unsigned short* __restrict__ Whi, const unsigned short* __restrict__ Wlo,
    const unsigned short* __restrict__ Xhi, const unsigned short* __restrict__ Xlo,
    unsigned short* H0hi, unsigned short* H1hi,
    float* __restrict__ Hf32,
    const float* __restrict__ bg, const float* __restrict__ bi,
    const float* __restrict__ bf_, const float* __restrict__ bo,
    unsigned* flags) {
    extern __shared__ unsigned short lds[];
    unsigned short* Lhi = lds;                    // [64][LROW]
    unsigned short* Llo = lds + 64 * LROW;        // [64][LROW]
    unsigned short* Pp  = lds + 64 * LROW * 2;    // [16][PROW] panel buffer

    const int bid = blockIdx.x;
    const int rg  = bid >> 3;                  // row-group id (0..31)
    const int m0  = rg * 64;                   // stacked-row tile base
    const int ct  = bid & 7;                   // column-group id
    const int bn0 = ct * 32;
    const int tid = threadIdx.x;
    const int lane = tid & 63;
    const int w  = tid >> 6;                   // wave id: rows w*16..w*16+15
    const int lr = lane & 15, q = lane >> 4;

    // flags: one 64B line per WG: index (ct*32+rg)*16 uints
    unsigned* myflag = flags + (((ct << 5) + rg) << 4);
    unsigned* pollp  = flags + (((ct << 5) + (lane & 31)) << 4);

    // panel staging assignment: 16 threads per column
    const int c_l = tid >> 4;                  // 0..15 (col within half)
    const int jj  = tid & 15;                  // 32-short chunk within col

    // one-time weight staging global -> LDS
    for (int it = tid; it < 64 * 68; it += 256) {
        int r = it / 68, c8 = (it % 68) * 8;
        *(bf16x8*)&Lhi[r * LROW + c8] = ld8(Whi + (size_t)(m0 + r) * Kpad + c8);
        *(bf16x8*)&Llo[r * LROW + c8] = ld8(Wlo + (size_t)(m0 + r) * Kpad + c8);
    }
    __syncthreads();

    const int kq = q * 8;
    const int col0 = bn0 + lr;                 // acc0 cell column
    const int col1 = col0 + 16;                // acc1 cell column
    const int i0 = (m0 >> 2) + w * 4 + q;      // h-row of both cells (R1-verified)

    float c0 = 0.f, c1 = 0.f;
    const f32x4 binit = { bg[i0], bi[i0], bf_[i0], bo[i0] };

    const unsigned short* Ah = &Lhi[(w * 16 + lr) * LROW + kq];
    const unsigned short* Al = &Llo[(w * 16 + lr) * LROW + kq];
    const unsigned short* Bl = &Pp[lr * PROW + kq];
    unsigned short* Pd = &Pp[c_l * PROW + jj * 32];

    for (int t = 0; t < Tdim; ++t) {
        const unsigned short* Rh = (t & 1) ? H1hi : H0hi;
        unsigned short* Wh = (t & 1) ? H0hi : H1hi;

        // ---- issue ALL panel loads for both halves (batched agent u64) ----
        u64 r0[8], r1[8];
        {
            const u64* s0 = (const u64*)(Rh + (size_t)(bn0 + c_l) * Hdim) + (size_t)jj * 8;
            const u64* s1 = (const u64*)(Rh + (size_t)(bn0 + 16 + c_l) * Hdim) + (size_t)jj * 8;
#pragma unroll
            for (int v2 = 0; v2 < 8; ++v2) r0[v2] = ldA(s0 + v2);
#pragma unroll
            for (int v2 = 0; v2 < 8; ++v2) r1[v2] = ldA(s1 + v2);
        }
        // x fragments for this lane's two columns (read-only, cached)
        const unsigned short* xb  = Xhi + ((size_t)t * Bdim) * 32;
        const unsigned short* xbl = Xlo + ((size_t)t * Bdim) * 32;
        bf16x8 xh0 = ld8(xb + col0 * 32 + kq), xl0 = ld8(xbl + col0 * 32 + kq);
        bf16x8 xh1 = ld8(xb + col1 * 32 + kq), xl1 = ld8(xbl + col1 * 32 + kq);

        // ---- half0 (cols 0-15) -> LDS, consume into acc0 ----
        {
            u64* d = (u64*)Pd;
#pragma unroll
            for (int v2 = 0; v2 < 8; ++v2) d[v2] = r0[v2];
        }
        __syncthreads();
        f32x4 acc0 = binit, acc1 = binit;
#pragma unroll
        for (int kb = 0; kb < 16; ++kb) {
            const int k = kb * 32;
            bf16x8 ah = ld8(Ah + k), al = ld8(Al + k);
            bf16x8 bh = ld8(Bl + k);
            acc0 = mfma16(ah, bh, acc0);
            acc0 = mfma16(al, bh, acc0);
        }
        {   // x tail acc0
            bf16x8 ah = ld8(Ah + 512), al = ld8(Al + 512);
            acc0 = mfma16(ah, xh0, acc0);
            acc0 = mfma16(ah, xl0, acc0);
            acc0 = mfma16(al, xh0, acc0);
        }
        __syncthreads();     // all waves done reading half0

        // ---- half1 (cols 16-31) -> LDS, consume into acc1 ----
        {
            u64* d = (u64*)Pd;
#pragma unroll
            for (int v2 = 0; v2 < 8; ++v2) d[v2] = r1[v2];
        }
        __syncthreads();
#pragma unroll
        for (int kb = 0; kb < 16; ++kb) {
            const int k = kb * 32;
            bf16x8 ah = ld8(Ah + k), al = ld8(Al + k);
            bf16x8 bh = ld8(Bl + k);
            acc1 = mfma16(ah, bh, acc1);
            acc1 = mfma16(al, bh, acc1);
        }
        {   // x tail acc1
            bf16x8 ah = ld8(Ah + 512), al = ld8(Al + 512);
            acc1 = mfma16(ah, xh1, acc1);
            acc1 = mfma16(ah, xl1, acc1);
            acc1 = mfma16(al, xh1, acc1);
        }

        {   // cell (i0, col0)
            float g = tanh_fast(acc0[0]), ii = sigm(acc0[1]);
            float f = sigm(acc0[2]),      o  = sigm(acc0[3]);
            c0 = g * ii + c0 * f;
            float h = tanh_fast(c0) * o;
            size_t idx = (size_t)col0 * Hdim + i0;
            stH(Wh + idx, f2bf(h));
            if (t == Tdim - 1) Hf32[idx] = h;
        }
        {   // cell (i0, col1)
            float g = tanh_fast(acc1[0]), ii = sigm(acc1[1]);
            float f = sigm(acc1[2]),      o  = sigm(acc1[3]);
            c1 = g * ii + c1 * f;
            float h = tanh_fast(c1) * o;
            size_t idx = (size_t)col1 * Hdim + i0;
            stH(Wh + idx, f2bf(h));
            if (t == Tdim - 1) Hf32[idx] = h;
        }

        // ---- column-group barrier (R9-proven): flags + wave0 parallel poll ----
        asm volatile("s_waitcnt vmcnt(0)" ::: "memory");  // h stores acked at L3
        __syncthreads();                                  // all waves drained
        if (w == 0) {
            if (lane == 0)
                __hip_atomic_store(myflag, (unsigned)(t + 1),
                                   __ATOMIC_RELAXED, __HIP_MEMORY_SCOPE_AGENT);
            const unsigned tgt = (unsigned)(t + 1);
            bool ok = lane >= 32;                         // lanes 0..31 poll WG lane
            int guard = 1 << 16;  // bounded: pathological case -> no hang
            while (!ok && --guard) {
                unsigned v = __hip_atomic_load(pollp, __ATOMIC_RELAXED,
                                               __HIP_MEMORY_SCOPE_AGENT);
                ok = (v >= tgt);
                if (!ok) __builtin_amdgcn_s_sleep(1);     // pace the fabric traffic
            }
        }
        __syncthreads();
        asm volatile("" ::: "memory");   // no panel-load hoisting above barrier
    }
}

// ---------- output: logits + softmax, one block per batch element ----------
__global__ __launch_bounds__(64) void k_out(
    const float* __restrict__ Hf32, const float* __restrict__ w_out,
    const float* __restrict__ b_out, float* __restrict__ out) {
    int b = blockIdx.x;
    int lane = threadIdx.x;
    const f32x4* h4 = (const f32x4*)(Hf32 + (size_t)b * 512);
    f32x4 h0 = h4[lane * 2], h1 = h4[lane * 2 + 1];
    float acc[10];
#pragma unroll
    for (int c = 0; c < 10; ++c) {
        const f32x4* w4 = (const f32x4*)(w_out + c * 512);
        f32x4 w0 = w4[lane * 2], w1 = w4[lane * 2 + 1];
        acc[c] = h0[0]*w0[0] + h0[1]*w0[1] + h0[2]*w0[2] + h0[3]*w0[3]
               + h1[0]*w1[0] + h1[1]*w1[1] + h1[2]*w1[2] + h1[3]*w1[3];
    }
#pragma unroll
    for (int s = 32; s >= 1; s >>= 1)
#pragma unroll
        for (int c = 0; c < 10; ++c) acc[c] += __shfl_xor(acc[c], s, 64);
    if (lane == 0) {
        float logit[10];
#pragma unroll
        for (int c = 0; c < 10; ++c) logit[c] = acc[c] + b_out[c];
        float m = logit[0];
#pragma unroll
        for (int c = 1; c < 10; ++c) m = fmaxf(m, logit[c]);
        float e[10], sum = 0.f;
#pragma unroll
        for (int c = 0; c < 10; ++c) { e[c] = __expf(logit[c] - m); sum += e[c]; }
        float inv = 1.f / sum;
#pragma unroll
        for (int c = 0; c < 10; ++c) out[b * 10 + c] = e[c] * inv;
    }
}

extern "C" void kernel_launch(void* const* d_in, const int* in_sizes, int n_in,
                              void* d_out, int out_size, void* d_ws, size_t ws_size,
                              hipStream_t stream) {
    const float* x    = (const float*)d_in[0];
    const float* w_gx = (const float*)d_in[1];
    const float* w_gh = (const float*)d_in[2];
    const float* b_g  = (const float*)d_in[3];
    const float* w_ix = (const float*)d_in[4];
    const float* w_ih = (const float*)d_in[5];
    const float* b_i  = (const float*)d_in[6];
    const float* w_fx = (const float*)d_in[7];
    const float* w_fh = (const float*)d_in[8];
    const float* b_f  = (const float*)d_in[9];
    const float* w_ox = (const float*)d_in[10];
    const float* w_oh = (const float*)d_in[11];
    const float* b_o  = (const float*)d_in[12];
    const float* w_out = (const float*)d_in[13];
    const float* b_out = (const float*)d_in[14];
    float* out = (float*)d_out;

    char* ws = (char*)d_ws;
    size_t off = 0;
    auto alloc = [&](size_t bytes) { void* p = ws + off; off += (bytes + 255) & ~255ull; return p; };
    // flags | H0hi contiguous -> one zeroing kernel
    unsigned*       flags = (unsigned*)alloc(16384);      // 256 WG-flags, 64B apart
    unsigned short* H0hi  = (unsigned short*)alloc((size_t)Bdim * 512 * 2);
    unsigned short* H1hi  = (unsigned short*)alloc((size_t)Bdim * 512 * 2);
    float*          Hf32  = (float*)alloc((size_t)Bdim * 512 * 4);
    unsigned short* Whi   = (unsigned short*)alloc(2048ull * Kpad * 2);
    unsigned short* Wlo   = (unsigned short*)alloc(2048ull * Kpad * 2);
    unsigned short* Xhi   = (unsigned short*)alloc((size_t)Tdim * Bdim * 32 * 2);
    unsigned short* Xlo   = (unsigned short*)alloc((size_t)Tdim * Bdim * 32 * 2);
    (void)ws_size; (void)in_sizes; (void)n_in; (void)out_size;

    k_prep_w<<<(2048 * Kpad + 255) / 256, 256, 0, stream>>>(
        w_gh, w_ih, w_fh, w_oh, w_gx, w_ix, w_fx, w_ox, Whi, Wlo);
    k_prep_x<<<(Tdim * Bdim * 32 + 255) / 256, 256, 0, stream>>>(x, Xhi, Xlo);
    // zero flags+H0hi: 16384 + 262144 B = 69,632 floats = 272 blocks
    k_zero<<<272, 256, 0, stream>>>((float*)flags);

    hipFuncSetAttribute((const void*)k_persist,
                        hipFuncAttributeMaxDynamicSharedMemorySize, LDS_BYTES);
    k_persist<<<dim3(256), dim3(256), LDS_BYTES, stream>>>(
        Whi, Wlo, Xhi, Xlo, H0hi, H1hi,
        Hf32, b_g, b_i, b_f, b_o, flags);

    k_out<<<256, 64, 0, stream>>>(Hf32, w_out, b_out, out);
}